// Round 4
// baseline (159.666 us; speedup 1.0000x reference)
//
#include <hip/hip_runtime.h>

#define NN 4
#define CC 20
#define HH 64
#define WW 2048
#define CG 4           // channel groups
#define CPG (CC / CG)  // 5 channels per group
#define PX 4           // pixels per thread (w)
#define HT 2           // output rows per thread (h)

// 4 px x 2 rows per thread, 5 channels per block, branchless mask,
// float4 window loads, XCD-locality block swizzle.
__global__ __launch_bounds__(256, 3) void lc_xyz_kernel(
    const float* __restrict__ xyz,
    const float* __restrict__ softmax,
    const int* __restrict__ mask,
    float* __restrict__ out)
{
    // 1D grid, 1024 blocks. Fastest-varying index = (n,cg) so that, under
    // round-robin block->XCD dispatch, each (n,cg) keeps all its h-rows on
    // one XCD (softmax halo stays L2-resident).
    const int bid = blockIdx.x;
    const int nz  = bid & 15;       // 0..15 : n*4+cg
    const int r   = bid >> 4;       // 0..63
    const int wb  = r & 1;          // which w-half
    const int yb  = r >> 1;         // 0..31 : h-pair
    const int n   = nz >> 2;
    const int cg  = nz & 3;

    const int hw = HH * WW;
    const int t  = wb * 256 + threadIdx.x;   // pixel-quad index in row, 0..511
    const int p0 = t * PX;
    const int h0 = yb * HT;

    const float* xb  = xyz     + (size_t)n * 3  * hw;
    const float* smb = softmax + (size_t)n * CC * hw + (size_t)(cg * CPG) * hw;
    const int*   mb  = mask    + (size_t)n * hw;

    // Center coordinates for both output rows.
    float cx[HT][PX], cy[HT][PX], cz[HT][PX];
#pragma unroll
    for (int orow = 0; orow < HT; ++orow) {
        const int ctr = (h0 + orow) * WW + p0;
        const float4 a = *(const float4*)(xb + 0 * hw + ctr);
        const float4 b = *(const float4*)(xb + 1 * hw + ctr);
        const float4 c = *(const float4*)(xb + 2 * hw + ctr);
        cx[orow][0]=a.x; cx[orow][1]=a.y; cx[orow][2]=a.z; cx[orow][3]=a.w;
        cy[orow][0]=b.x; cy[orow][1]=b.y; cy[orow][2]=b.z; cy[orow][3]=b.w;
        cz[orow][0]=c.x; cz[orow][1]=c.y; cz[orow][2]=c.z; cz[orow][3]=c.w;
    }

    float acc[CPG][HT][PX];
#pragma unroll
    for (int c = 0; c < CPG; ++c)
#pragma unroll
        for (int orow = 0; orow < HT; ++orow)
#pragma unroll
            for (int i = 0; i < PX; ++i) acc[c][orow][i] = 0.f;

    // w-window: j=0..11 maps to w = p0-4+j; taps use j = i+dx+2 in [2,9].
    // Aligned 16B chunks at p0-4, p0, p0+4; edge chunks clamped (invalid taps
    // zeroed via vf; all VALID taps come from unclamped chunks).
    int c0 = p0 - 4; if (c0 < 0) c0 = 0;
    const int c1 = p0;
    int c2 = p0 + 4; if (c2 > WW - 4) c2 = WW - 4;

    float vf[12];
#pragma unroll
    for (int j = 2; j <= 9; ++j)
        vf[j] = ((unsigned)(p0 - 4 + j) < (unsigned)WW) ? 1.f : 0.f;

    // Tap rows h0-2 .. h0+3 (k = 0..5). Out row 'orow' uses k in [orow, orow+4].
#pragma unroll
    for (int k = 0; k < HT + 4; ++k) {
        const int row = h0 - 2 + k;
        if ((unsigned)row >= (unsigned)HH) continue;   // block-uniform
        const int rb = row * WW;

        // Batched independent row loads: 3 int4 + 9 float4.
        const int4 m0 = *(const int4*)(mb + rb + c0);
        const int4 m1 = *(const int4*)(mb + rb + c1);
        const int4 m2 = *(const int4*)(mb + rb + c2);
        const float4 x0 = *(const float4*)(xb + 0 * hw + rb + c0);
        const float4 x1 = *(const float4*)(xb + 0 * hw + rb + c1);
        const float4 x2 = *(const float4*)(xb + 0 * hw + rb + c2);
        const float4 y0 = *(const float4*)(xb + 1 * hw + rb + c0);
        const float4 y1 = *(const float4*)(xb + 1 * hw + rb + c1);
        const float4 y2 = *(const float4*)(xb + 1 * hw + rb + c2);
        const float4 z0 = *(const float4*)(xb + 2 * hw + rb + c0);
        const float4 z1 = *(const float4*)(xb + 2 * hw + rb + c1);
        const float4 z2 = *(const float4*)(xb + 2 * hw + rb + c2);

        const float xw[12] = {x0.x,x0.y,x0.z,x0.w, x1.x,x1.y,x1.z,x1.w, x2.x,x2.y,x2.z,x2.w};
        const float yw[12] = {y0.x,y0.y,y0.z,y0.w, y1.x,y1.y,y1.z,y1.w, y2.x,y2.y,y2.z,y2.w};
        const float zw[12] = {z0.x,z0.y,z0.z,z0.w, z1.x,z1.y,z1.z,z1.w, z2.x,z2.y,z2.z,z2.w};
        const int   mi[12] = {m0.x,m0.y,m0.z,m0.w, m1.x,m1.y,m1.z,m1.w, m2.x,m2.y,m2.z,m2.w};

        float mf[12];
#pragma unroll
        for (int j = 2; j <= 9; ++j) mf[j] = vf[j] * (float)mi[j];

        // Gaussian weights for each active out row (compile-time selection).
        float g[HT][PX][5];
#pragma unroll
        for (int orow = 0; orow < HT; ++orow) {
            if (k < orow || k > orow + 4) continue;    // compile-time after unroll
#pragma unroll
            for (int i = 0; i < PX; ++i) {
#pragma unroll
                for (int dx = 0; dx < 5; ++dx) {
                    const int j = i + dx + 2;
                    const float ax = xw[j] - cx[orow][i];
                    const float ay = yw[j] - cy[orow][i];
                    const float az = zw[j] - cz[orow][i];
                    const float d2 = ax * ax + ay * ay + az * az;
                    g[orow][i][dx] = mf[j] * __expf(-0.5f * d2);
                }
            }
        }

        // Channel loop: 3 float4 loads per channel, FMA into both out rows.
#pragma unroll
        for (int c = 0; c < CPG; ++c) {
            const float* sp = smb + (size_t)c * hw + rb;
            const float4 s0 = *(const float4*)(sp + c0);
            const float4 s1 = *(const float4*)(sp + c1);
            const float4 s2 = *(const float4*)(sp + c2);
            const float sw[12] = {s0.x,s0.y,s0.z,s0.w, s1.x,s1.y,s1.z,s1.w, s2.x,s2.y,s2.z,s2.w};
#pragma unroll
            for (int orow = 0; orow < HT; ++orow) {
                if (k < orow || k > orow + 4) continue;
#pragma unroll
                for (int i = 0; i < PX; ++i) {
                    float a = acc[c][orow][i];
#pragma unroll
                    for (int dx = 0; dx < 5; ++dx)
                        a = fmaf(g[orow][i][dx], sw[i + dx + 2], a);
                    acc[c][orow][i] = a;
                }
            }
        }
    }

    // Store 2 rows x 5 channels as float4.
#pragma unroll
    for (int orow = 0; orow < HT; ++orow) {
        float* ob = out + (size_t)n * CC * hw + (size_t)(cg * CPG) * hw
                  + (h0 + orow) * WW + p0;
#pragma unroll
        for (int c = 0; c < CPG; ++c)
            *(float4*)(ob + (size_t)c * hw) =
                make_float4(acc[c][orow][0], acc[c][orow][1],
                            acc[c][orow][2], acc[c][orow][3]);
    }
}

extern "C" void kernel_launch(void* const* d_in, const int* in_sizes, int n_in,
                              void* d_out, int out_size, void* d_ws, size_t ws_size,
                              hipStream_t stream) {
    const float* xyz     = (const float*)d_in[0];
    const float* softmax = (const float*)d_in[1];
    const int*   mask    = (const int*)d_in[2];
    float*       out     = (float*)d_out;

    dim3 block(256, 1, 1);
    dim3 grid((WW / (PX * 256)) * (HH / HT) * NN * CG, 1, 1);  // 1024 blocks, 1D
    hipLaunchKernelGGL(lc_xyz_kernel, grid, block, 0, stream,
                       xyz, softmax, mask, out);
}